// Round 16
// baseline (229.064 us; speedup 1.0000x reference)
//
#include <hip/hip_runtime.h>
#include <math.h>

#define BB 8
#define CC 64
#define NN 4096
#define COUT 64
#define KK 20
#define NQ 32768

// NumPy-exact (FMA-free, left-to-right) distance pieces. np.einsum / np.sum
// round every mul and add individually; __f*_rn intrinsics forbid contraction.
__device__ __forceinline__ float np_sq(float ax, float ay, float az) {
    return __fadd_rn(__fadd_rn(__fmul_rn(ax, ax), __fmul_rn(ay, ay)), __fmul_rn(az, az));
}
__device__ __forceinline__ float np_dist(float qx, float qy, float qz, float sqn, float4 p) {
    float dot = __fadd_rn(__fadd_rn(__fmul_rn(qx, p.x), __fmul_rn(qy, p.y)), __fmul_rn(qz, p.z));
    return __fsub_rn(__fadd_rn(sqn, p.w), __fmul_rn(2.0f, dot));
}
__device__ __forceinline__ float min3f(float a, float b, float c) { return fminf(fminf(a, b), c); }
__device__ __forceinline__ float max3f(float a, float b, float c) { return fmaxf(fmaxf(a, b), c); }

// order-preserving float->uint map (handles the tiny-negative rounding case)
__device__ __forceinline__ unsigned long long dm_key(float d, int m) {
    unsigned u = __float_as_uint(d);
    u ^= (unsigned)((int)u >> 31) | 0x80000000u;
    return ((unsigned long long)u << 32) | (unsigned)m;
}

// ---------------- K1a: per-chunk top-SLOTS distances, carry-4 med3 network ----------------
// Stages from x directly (np_sq inline, bit-identical to the old prep); designated
// blocks ((grp&15)==0, one grp per batch) also publish pts4 for knn_collect.
// No self-mask: d(self) == exactly +0 -> strict chunk min -> bd[0] of self chunk;
// knn_tau drops that one entry.
template <int NCH, int SLOTS>
__global__ __launch_bounds__(256) void knn_part(const float* __restrict__ x,
                                                float4* __restrict__ pts4,
                                                float* __restrict__ pd) {
    constexpr int CH = NN / NCH;
    const int grp = blockIdx.x / NCH;
    const int ch = blockIdx.x % NCH;
    const int tid = threadIdx.x;
    const int q = grp * 256 + tid;
    const int b = q >> 12;
    const int n = q & (NN - 1);
    const float* xb = x + (size_t)b * CC * NN;
    const bool writer = ((grp & 15) == 0);        // 16 grps/batch -> one writer grp each

    __shared__ float4 pts[CH];
    for (int i = tid; i < CH; i += 256) {
        int m = ch * CH + i;
        float ax = xb[m], ay = xb[NN + m], az = xb[2 * NN + m];
        float4 v = make_float4(ax, ay, az, np_sq(ax, ay, az));
        pts[i] = v;
        if (writer) pts4[(size_t)b * NN + m] = v;
    }
    __syncthreads();

    float qax = xb[n], qay = xb[NN + n], qaz = xb[2 * NN + n];
    const float qx = qax, qy = qay, qz = qaz;
    const float sqn = np_sq(qax, qay, qaz);

    float bd[SLOTS];
#pragma unroll
    for (int i = 0; i < SLOTS; ++i) bd[i] = INFINITY;

#pragma unroll 4
    for (int i = 0; i < CH; i += 4) {
        float4 p0 = pts[i + 0], p1 = pts[i + 1], p2 = pts[i + 2], p3 = pts[i + 3];
        float d0 = np_dist(qx, qy, qz, sqn, p0);
        float d1 = np_dist(qx, qy, qz, sqn, p1);
        float d2 = np_dist(qx, qy, qz, sqn, p2);
        float d3 = np_dist(qx, qy, qz, sqn, p3);
        float a0 = fminf(d0, d1), a1 = fmaxf(d0, d1);
        float b0 = fminf(d2, d3), b1 = fmaxf(d2, d3);
        // carry-4: extract min of {a0,b0,bd[s]}, restructure remainder as 2 sorted pairs
#pragma unroll
        for (int s = 0; s < SLOTS; ++s) {
            float mn = min3f(a0, b0, bd[s]);
            float md = __builtin_amdgcn_fmed3f(a0, b0, bd[s]);
            float mx = max3f(a0, b0, bd[s]);
            float t0 = fminf(a1, b1);
            float t1 = fmaxf(a1, b1);
            bd[s] = mn;
            a0 = md; a1 = mx;    // A' = (med3, max3), sorted
            b0 = t0; b1 = t1;    // B' = sort(old a1, old b1)
        }
    }

    // pd layout [chunk][j][q] -> coalesced stores
#pragma unroll
    for (int j = 0; j < SLOTS; ++j) pd[(size_t)(ch * SLOTS + j) * NQ + q] = bd[j];
}

// r-th smallest (r=1..R) of sorted a[LA] u sorted b[LB]; infeasible splits masked by +/-INF
template <int LA, int LB, int R>
__device__ __forceinline__ void mergeR(const float* a, const float* b, float* out) {
#pragma unroll
    for (int r = 1; r <= R; ++r) {
        float best = INFINITY;
#pragma unroll
        for (int j = 0; j <= R; ++j) {
            if (j <= r) {
                float av = (j >= 1) ? ((j <= LA) ? a[j - 1] : INFINITY) : -INFINITY;
                float bv = (r - j >= 1) ? ((r - j <= LB) ? b[r - j - 1] : INFINITY) : -INFINITY;
                best = fminf(best, fmaxf(av, bv));
            }
        }
        out[r - 1] = best;
    }
}

// ---------------- K1b: tau + mode from truncated per-chunk lists ----------------
//   0  -> surplus==0: accepting ALL d<=tau (ascending m) is exactly the stable top-20
//   >0 -> exact tie budget (rank ties, ascending m)            [measure-zero case]
//   -1 -> truncation flag tripped: wave-parallel exact fallback [~25 queries/run at LEN=8]
template <int NCH, int SLOTS>
__global__ __launch_bounds__(256) void knn_tau(const float* __restrict__ pd,
                                               float* __restrict__ taubuf,
                                               int* __restrict__ budgetbuf) {
    const int q = blockIdx.x * 256 + threadIdx.x;   // 128 blocks
    constexpr int CH = NN / NCH;
    constexpr int LEN = SLOTS - 1;                  // effective list length (self dropped)
    const int ch_self = (q & (NN - 1)) / CH;

    float L[NCH][LEN];
#pragma unroll
    for (int c = 0; c < NCH; ++c) {
        float raw[SLOTS];
#pragma unroll
        for (int j = 0; j < SLOTS; ++j) raw[j] = pd[(size_t)(c * SLOTS + j) * NQ + q];
        bool shift = (c == ch_self);   // drop self's exact-0 at slot 0
#pragma unroll
        for (int j = 0; j < LEN; ++j) L[c][j] = shift ? raw[j + 1] : raw[j];
    }

    float T[KK];
    mergeR<LEN, LEN, KK>(L[0], L[1], T);
#pragma unroll
    for (int c = 2; c < NCH; ++c) {
        float M[KK];
        mergeR<KK, LEN, KK>(T, L[c], M);
#pragma unroll
        for (int j = 0; j < KK; ++j) T[j] = M[j];
    }

    float tau = T[KK - 1];
    int cnt_lt = 0, cnt_eq = 0;
    bool flag = false;
#pragma unroll
    for (int c = 0; c < NCH; ++c) {
#pragma unroll
        for (int j = 0; j < LEN; ++j) {
            cnt_lt += (L[c][j] < tau) ? 1 : 0;
            cnt_eq += (L[c][j] == tau) ? 1 : 0;
        }
        flag = flag || (L[c][LEN - 1] <= tau);
    }
    int surplus = cnt_lt + cnt_eq - KK;             // >=0 when flag==0
    taubuf[q] = tau;
    budgetbuf[q] = flag ? -1 : (surplus == 0 ? 0 : (KK - cnt_lt));
}

// ---------------- K1c: collect ----------------
__device__ __forceinline__ int prefix_count(unsigned long long mask) {
    int r = __builtin_amdgcn_mbcnt_lo((unsigned)mask, 0);
    return __builtin_amdgcn_mbcnt_hi((unsigned)(mask >> 32), r);
}

#define FBCAP 128

// single-query exact collect: budget==0 / >0 / -1. Always fully writes erow.
// fbuf: per-wave LDS scratch (FBCAP u64) for the -1 wave-parallel fallback.
__device__ void collect_one(const float4* __restrict__ pb, int n, float qx, float qy,
                            float qz, float sqn, float tau, int budget, int lane,
                            unsigned long long* __restrict__ fbuf,
                            int* __restrict__ erow) {
    if (budget == 0) {
        int cnt = 0;
        for (int it = 0; it < 64; ++it) {
            int m = it * 64 + lane;
            float d = np_dist(qx, qy, qz, sqn, pb[m]);
            bool acc = (d <= tau) && (m != n);
            unsigned long long macc = __ballot(acc);
            if (macc) {
                int pos = cnt + prefix_count(macc);
                if (acc && pos < KK) erow[pos] = m;
                cnt += __popcll(macc);
            }
        }
        if (lane == 0) {   // backfill guard: edges must never retain poison
            for (int j = cnt; j < KK; ++j) erow[j] = (n + 1 + j) & (NN - 1);
        }
    } else if (budget > 0) {
        int cnt = 0, ties = 0;
        for (int it = 0; it < 64; ++it) {
            int m = it * 64 + lane;
            float d = np_dist(qx, qy, qz, sqn, pb[m]);
            bool valid = (m != n);
            bool is_lt = valid && (d < tau);
            bool is_tie = valid && (d == tau);
            unsigned long long mtie = __ballot(is_tie);
            int tie_rank = ties + prefix_count(mtie);
            bool acc = is_lt || (is_tie && tie_rank < budget);
            unsigned long long macc = __ballot(acc);
            int pos = cnt + prefix_count(macc);
            if (acc && pos < KK) erow[pos] = m;
            cnt += __popcll(macc);
            ties += __popcll(mtie);
        }
        if (lane == 0) {
            for (int j = cnt; j < KK; ++j) erow[j] = (n + 1 + j) & (NN - 1);
        }
    } else {
        // -1: tau (from truncated lists) >= true tau -> {d<=tau} superset of top-20.
        // Wave-parallel gather into LDS, then lane-0 exact (d,m)-key select.
        int cnt = 0;
        for (int it = 0; it < 64; ++it) {
            int m = it * 64 + lane;
            float d = np_dist(qx, qy, qz, sqn, pb[m]);
            bool acc = (d <= tau) && (m != n);
            unsigned long long macc = __ballot(acc);
            if (macc) {
                int pos = cnt + prefix_count(macc);
                if (acc && pos < FBCAP) fbuf[pos] = dm_key(d, m);
                cnt += __popcll(macc);
            }
        }
        if (cnt <= FBCAP) {
            if (lane == 0) {
                unsigned long long bk[KK];
#pragma unroll
                for (int j = 0; j < KK; ++j) bk[j] = ~0ULL;
                for (int i = 0; i < cnt; ++i) {
                    unsigned long long key = fbuf[i];
                    if (key < bk[KK - 1]) {
#pragma unroll
                        for (int s = KK - 1; s >= 1; --s) {
                            bool sh = bk[s - 1] > key;
                            bool here = bk[s] > key;
                            bk[s] = sh ? bk[s - 1] : (here ? key : bk[s]);
                        }
                        if (bk[0] > key) bk[0] = key;
                    }
                }
                for (int j = 0; j < KK; ++j) erow[j] = (int)(bk[j] & (NN - 1));
            }
        } else if (lane == 0) {
            // degenerate-data backstop: serial full scan (exact)
            unsigned long long bk[KK];
#pragma unroll
            for (int j = 0; j < KK; ++j) bk[j] = ~0ULL;
            for (int m = 0; m < NN; ++m) {
                if (m == n) continue;
                float d = np_dist(qx, qy, qz, sqn, pb[m]);
                unsigned long long key = dm_key(d, m);
                if (key < bk[KK - 1]) {
#pragma unroll
                    for (int s = KK - 1; s >= 1; --s) {
                        bool sh = bk[s - 1] > key;
                        bool here = bk[s] > key;
                        bk[s] = sh ? bk[s - 1] : (here ? key : bk[s]);
                    }
                    if (bk[0] > key) bk[0] = key;
                }
            }
            for (int j = 0; j < KK; ++j) erow[j] = (int)(bk[j] & (NN - 1));
        }
    }
}

// 8 queries per wave: one candidate load feeds 8 distance tests (L2 traffic /8).
__global__ __launch_bounds__(256) void knn_collect(const float4* __restrict__ pts4,
                                                   const float* __restrict__ taubuf,
                                                   const int* __restrict__ budgetbuf,
                                                   int* __restrict__ edges) {
    const int wave = threadIdx.x >> 6;
    const int lane = threadIdx.x & 63;
    const int q0 = (blockIdx.x * 4 + wave) * 8;
    const int b = q0 >> 12;                          // 8 | 4096 -> same batch for all 8
    const float4* pb = pts4 + (size_t)b * NN;
    __shared__ unsigned long long fbuf[4][FBCAP];    // 4 KB

    int nj[8], bj[8];
    float qxj[8], qyj[8], qzj[8], sqj[8], tj[8];
    int orb = 0;
#pragma unroll
    for (int j = 0; j < 8; ++j) {
        int q = q0 + j;
        nj[j] = q & (NN - 1);
        float4 me = pb[nj[j]];                       // uniform -> broadcast
        qxj[j] = me.x; qyj[j] = me.y; qzj[j] = me.z; sqj[j] = me.w;
        tj[j] = taubuf[q];
        bj[j] = budgetbuf[q];
        orb |= bj[j];
    }

    if (orb == 0) {                                  // wave-uniform fast gate
        int cnt[8] = {0, 0, 0, 0, 0, 0, 0, 0};
        for (int it = 0; it < 64; ++it) {
            int m = it * 64 + lane;
            float4 p = pb[m];                        // one coalesced b128 for 8 queries
#pragma unroll
            for (int j = 0; j < 8; ++j) {
                float d = np_dist(qxj[j], qyj[j], qzj[j], sqj[j], p);
                bool acc = (d <= tj[j]) && (m != nj[j]);
                unsigned long long mk = __ballot(acc);
                if (mk) {
                    int pos = cnt[j] + prefix_count(mk);
                    if (acc && pos < KK) edges[(size_t)(q0 + j) * KK + pos] = m;
                    cnt[j] += __popcll(mk);
                }
            }
        }
        if (lane == 0) {   // backfill guard: edges must never retain poison
#pragma unroll
            for (int j = 0; j < 8; ++j) {
                for (int t = cnt[j]; t < KK; ++t)
                    edges[(size_t)(q0 + j) * KK + t] = (nj[j] + 1 + t) & (NN - 1);
            }
        }
    } else {
        // rare: at least one query needs tie/fallback handling — do all 8 exactly
#pragma unroll
        for (int j = 0; j < 8; ++j) {
            collect_one(pb, nj[j], qxj[j], qyj[j], qzj[j], sqj[j], tj[j], bj[j], lane,
                        fbuf[wave], edges + (size_t)(q0 + j) * KK);
        }
    }
}

// ---------------- K2: projections P1 = (W1-W2)·x_n, P2 = W2·x_n ----------------
__global__ __launch_bounds__(256) void proj_kernel(const float* __restrict__ x,
                                                   const float* __restrict__ W,
                                                   float* __restrict__ P1,
                                                   float* __restrict__ P2) {
    const int wid = blockIdx.x * 4 + (threadIdx.x >> 6);  // 8192 = 512 row-blocks x 16 o-groups
    const int lane = threadIdx.x & 63;
    const int row_block = wid >> 4;
    const int og = __builtin_amdgcn_readfirstlane(wid & 15);
    const int row = row_block * 64 + lane;
    const int b = row >> 12;
    const int n = row & (NN - 1);
    const float* xb = x + (size_t)b * CC * NN;

    float p1[4] = {0.f, 0.f, 0.f, 0.f};
    float p2[4] = {0.f, 0.f, 0.f, 0.f};
#pragma unroll 8
    for (int c = 0; c < CC; ++c) {
        float xv = xb[(size_t)c * NN + n];                 // coalesced 256B
#pragma unroll
        for (int j = 0; j < 4; ++j) {
            int o = og * 4 + j;
            float w1 = W[o * 2 * CC + c];                  // scalar (s_load) — uniform
            float w2 = W[o * 2 * CC + CC + c];
            p1[j] += (w1 - w2) * xv;
            p2[j] += w2 * xv;
        }
    }
#pragma unroll
    for (int j = 0; j < 4; ++j) {
        int o = og * 4 + j;
        P1[(size_t)row * 64 + o] = p1[j];
        P2[(size_t)row * 64 + o] = p2[j];
    }
}

// ---------------- K3a: BN partial sums + per-row hmax -> transposed store into d_out --------
// XCD-batch swizzle: batch = blockIdx & 7 (L2-resident P2 per XCD); partials stay
// indexed by row-block id so downstream summation order is stable.
// ej clamped to [0,NN): a corrupt edge index can never read outside P2's batch slab.
__global__ __launch_bounds__(256) void stats_kernel(const float* __restrict__ P1,
                                                    const float* __restrict__ P2,
                                                    const int* __restrict__ edges,
                                                    float* __restrict__ partials,
                                                    float* __restrict__ out) {
    int blk = blockIdx.x;          // 512 blocks, 64 rows each
    int b = blk & 7;               // batch
    int inner = blk >> 3;          // 0..63
    int row0 = b * NN + inner * 64;
    int pblk = row0 >> 6;          // row-block id for partials (order-preserving)
    int o = threadIdx.x & 63;
    int rq = threadIdx.x >> 6;
    int n0 = row0 & (NN - 1);
    const float* P2b = P2 + (size_t)b * NN * 64;
    __shared__ float tile[64][65];
    float s = 0.f, s2 = 0.f;
    for (int rr = rq; rr < 64; rr += 4) {
        int row = row0 + rr;
        float p1 = P1[row * 64 + o];
        const int* e = edges + row * KK;
        float hm = -INFINITY;
#pragma unroll
        for (int j = 0; j < KK; ++j) {
            int ej = e[j] & (NN - 1);           // wave-uniform; clamped (safety)
            float v = p1 + P2b[ej * 64 + o];    // coalesced 256B gather (L2-resident)
            s += v;
            s2 += v * v;
            hm = fmaxf(hm, v);
        }
        tile[rr][o] = hm;
    }
    __shared__ float sh1[256], sh2[256];
    sh1[threadIdx.x] = s;
    sh2[threadIdx.x] = s2;
    __syncthreads();
    if (threadIdx.x < 64) {
        float a = sh1[threadIdx.x] + sh1[threadIdx.x + 64] + sh1[threadIdx.x + 128] + sh1[threadIdx.x + 192];
        float a2 = sh2[threadIdx.x] + sh2[threadIdx.x + 64] + sh2[threadIdx.x + 128] + sh2[threadIdx.x + 192];
        partials[pblk * 128 + threadIdx.x] = a;
        partials[pblk * 128 + 64 + threadIdx.x] = a2;
    }
    int w2 = threadIdx.x >> 6;
    int lane = threadIdx.x & 63;
    for (int o2 = w2 * 16; o2 < w2 * 16 + 16; ++o2) {
        out[((size_t)(b * 64 + o2)) * NN + n0 + lane] = tile[lane][o2];  // coalesced 256B
    }
}

// ---------------- K4: finalize BN (per-block) + elementwise act over hmax ----------------
// Each block computes A,Cv for its channel o by reducing the 512 partials rows
// (tree order; BN-const rounding shift ~1 ulp, harmless vs 0.11 threshold), then
// applies act in place. Monotone: max act == act(max h) for A>=0; exact fallback else.
__global__ __launch_bounds__(256) void out2_kernel(const float* __restrict__ P1,
                                                   const float* __restrict__ P2,
                                                   const int* __restrict__ edges,
                                                   const float* __restrict__ partials,
                                                   const float* __restrict__ gamma,
                                                   const float* __restrict__ beta,
                                                   float* __restrict__ out) {
    const int blk = blockIdx.x;        // 512 = b*64 + o
    const int b = blk >> 6;
    const int o = blk & 63;
    const int t = threadIdx.x;

    __shared__ float r1[256], r2[256];
    r1[t] = partials[t * 128 + o] + partials[(t + 256) * 128 + o];
    r2[t] = partials[t * 128 + 64 + o] + partials[(t + 256) * 128 + 64 + o];
    __syncthreads();
    for (int step = 128; step >= 1; step >>= 1) {
        if (t < step) { r1[t] += r1[t + step]; r2[t] += r2[t + step]; }
        __syncthreads();
    }
    __shared__ float sA, sC;
    if (t == 0) {
        const float M = (float)((size_t)BB * NN * KK);  // 655360
        float mean = r1[0] / M;
        float var = r2[0] / M - mean * mean;
        float inv = 1.0f / sqrtf(var + 1e-5f);
        float A = gamma[o] * inv;
        sA = A;
        sC = beta[o] - mean * A;
    }
    __syncthreads();
    const float A = sA;
    const float Cv = sC;

    float* orow = out + (size_t)blk * NN;   // out[b][o][:]
    if (A >= 0.f) {
#pragma unroll
        for (int it = 0; it < 4; ++it) {
            int idx = (it * 256 + t) * 4;
            float4 v = *(const float4*)(orow + idx);
            float h0 = v.x * A + Cv, h1 = v.y * A + Cv, h2 = v.z * A + Cv, h3 = v.w * A + Cv;
            v.x = h0 >= 0.f ? h0 : 0.2f * h0;
            v.y = h1 >= 0.f ? h1 : 0.2f * h1;
            v.z = h2 >= 0.f ? h2 : 0.2f * h2;
            v.w = h3 >= 0.f ? h3 : 0.2f * h3;
            *(float4*)(orow + idx) = v;
        }
    } else {
        // exact fallback (A<0 flips monotonicity) — never taken for this data
        const float* P2b = P2 + (size_t)b * NN * 64;
        for (int n = t; n < NN; n += 256) {
            size_t row = (size_t)b * NN + n;
            float p1 = P1[row * 64 + o];
            const int* e = edges + row * KK;
            float mx = -INFINITY;
            for (int j = 0; j < KK; ++j) {
                int ej = e[j] & (NN - 1);       // clamped (safety)
                float h = p1 + P2b[ej * 64 + o];
                float hn = h * A + Cv;
                mx = fmaxf(mx, hn >= 0.f ? hn : 0.2f * hn);
            }
            orow[n] = mx;
        }
    }
}

extern "C" void kernel_launch(void* const* d_in, const int* in_sizes, int n_in,
                              void* d_out, int out_size, void* d_ws, size_t ws_size,
                              hipStream_t stream) {
    const float* x = (const float*)d_in[0];
    const float* W = (const float*)d_in[1];
    const float* gamma = (const float*)d_in[2];
    const float* beta = (const float*)d_in[3];
    float* out = (float*)d_out;

    // De-aliased layout: only pd shares memory (with P1/P2, dead before proj writes).
    char* w = (char*)d_ws;
    float4* pts4      = (float4*)(w + 0);                 //   524288 B
    float*  taubuf    = (float*)(w + 524288);             //   131072 B
    int*    budgetbuf = (int*)(w + 655360);               //   131072 B
    float*  partials  = (float*)(w + 786432);             //   262144 B
    int*    edges     = (int*)(w + 1049600);              //  2621440 B
    char*   region    = w + 3671040;
    float*  P1 = (float*)region;                          //  8388608 B
    float*  P2 = P1 + (size_t)NQ * 64;                    //  8388608 B
    float*  pd = (float*)region;                          // aliases P1/P2 head

    const size_t needA = 3671040 + (size_t)16 * 9 * NQ * 4;   // 22,545,408 B (known to fit)

    if (ws_size >= needA) {
        knn_part<16, 9><<<128 * 16, 256, 0, stream>>>(x, pts4, pd);
        knn_tau<16, 9><<<128, 256, 0, stream>>>(pd, taubuf, budgetbuf);
    } else {
        knn_part<8, 13><<<128 * 8, 256, 0, stream>>>(x, pts4, pd);
        knn_tau<8, 13><<<128, 256, 0, stream>>>(pd, taubuf, budgetbuf);
    }
    knn_collect<<<1024, 256, 0, stream>>>(pts4, taubuf, budgetbuf, edges);

    proj_kernel<<<2048, 256, 0, stream>>>(x, W, P1, P2);
    stats_kernel<<<512, 256, 0, stream>>>(P1, P2, edges, partials, out);
    out2_kernel<<<512, 256, 0, stream>>>(P1, P2, edges, partials, gamma, beta, out);
}

// Round 17
// 181.130 us; speedup vs baseline: 1.2646x; 1.2646x over previous
//
#include <hip/hip_runtime.h>
#include <math.h>

#define BB 8
#define CC 64
#define NN 4096
#define COUT 64
#define KK 20
#define NQ 32768

// NumPy-exact (FMA-free, left-to-right) distance pieces. np.einsum / np.sum
// round every mul and add individually; __f*_rn intrinsics forbid contraction.
__device__ __forceinline__ float np_sq(float ax, float ay, float az) {
    return __fadd_rn(__fadd_rn(__fmul_rn(ax, ax), __fmul_rn(ay, ay)), __fmul_rn(az, az));
}
__device__ __forceinline__ float np_dist(float qx, float qy, float qz, float sqn, float4 p) {
    float dot = __fadd_rn(__fadd_rn(__fmul_rn(qx, p.x), __fmul_rn(qy, p.y)), __fmul_rn(qz, p.z));
    return __fsub_rn(__fadd_rn(sqn, p.w), __fmul_rn(2.0f, dot));
}
__device__ __forceinline__ float min3f(float a, float b, float c) { return fminf(fminf(a, b), c); }
__device__ __forceinline__ float max3f(float a, float b, float c) { return fmaxf(fmaxf(a, b), c); }

// ---------------- K1a: per-chunk top-SLOTS distances, carry-4 med3 network ----------------
// Fused prep: stages from x directly (np_sq inline, bit-identical to old prep);
// designated writer grp per batch also publishes pts4 for knn_collect.
// No self-mask: d(self) == exactly +0 -> strict chunk min -> bd[0] of self chunk;
// knn_tau drops that one entry.
template <int NCH, int SLOTS>
__global__ __launch_bounds__(256) void knn_part(const float* __restrict__ x,
                                                float4* __restrict__ pts4,
                                                float* __restrict__ pd) {
    constexpr int CH = NN / NCH;
    const int grp = blockIdx.x / NCH;
    const int ch = blockIdx.x % NCH;
    const int tid = threadIdx.x;
    const int q = grp * 256 + tid;
    const int b = q >> 12;
    const int n = q & (NN - 1);
    const float* xb = x + (size_t)b * CC * NN;
    const bool writer = ((grp & 15) == 0);        // 16 grps/batch -> one writer grp each

    __shared__ float4 pts[CH];
    for (int i = tid; i < CH; i += 256) {
        int m = ch * CH + i;
        float ax = xb[m], ay = xb[NN + m], az = xb[2 * NN + m];
        float4 v = make_float4(ax, ay, az, np_sq(ax, ay, az));
        pts[i] = v;
        if (writer) pts4[(size_t)b * NN + m] = v;
    }
    __syncthreads();

    float qax = xb[n], qay = xb[NN + n], qaz = xb[2 * NN + n];
    const float qx = qax, qy = qay, qz = qaz;
    const float sqn = np_sq(qax, qay, qaz);

    float bd[SLOTS];
#pragma unroll
    for (int i = 0; i < SLOTS; ++i) bd[i] = INFINITY;

#pragma unroll 4
    for (int i = 0; i < CH; i += 4) {
        float4 p0 = pts[i + 0], p1 = pts[i + 1], p2 = pts[i + 2], p3 = pts[i + 3];
        float d0 = np_dist(qx, qy, qz, sqn, p0);
        float d1 = np_dist(qx, qy, qz, sqn, p1);
        float d2 = np_dist(qx, qy, qz, sqn, p2);
        float d3 = np_dist(qx, qy, qz, sqn, p3);
        float a0 = fminf(d0, d1), a1 = fmaxf(d0, d1);
        float b0 = fminf(d2, d3), b1 = fmaxf(d2, d3);
        // carry-4: extract min of {a0,b0,bd[s]}, restructure remainder as 2 sorted pairs
#pragma unroll
        for (int s = 0; s < SLOTS; ++s) {
            float mn = min3f(a0, b0, bd[s]);
            float md = __builtin_amdgcn_fmed3f(a0, b0, bd[s]);
            float mx = max3f(a0, b0, bd[s]);
            float t0 = fminf(a1, b1);
            float t1 = fmaxf(a1, b1);
            bd[s] = mn;
            a0 = md; a1 = mx;    // A' = (med3, max3), sorted
            b0 = t0; b1 = t1;    // B' = sort(old a1, old b1)
        }
    }

    // pd layout [chunk][j][q] -> coalesced stores
#pragma unroll
    for (int j = 0; j < SLOTS; ++j) pd[(size_t)(ch * SLOTS + j) * NQ + q] = bd[j];
}

// r-th smallest (r=1..R) of sorted a[LA] u sorted b[LB]; infeasible splits masked by +/-INF
template <int LA, int LB, int R>
__device__ __forceinline__ void mergeR(const float* a, const float* b, float* out) {
#pragma unroll
    for (int r = 1; r <= R; ++r) {
        float best = INFINITY;
#pragma unroll
        for (int j = 0; j <= R; ++j) {
            if (j <= r) {
                float av = (j >= 1) ? ((j <= LA) ? a[j - 1] : INFINITY) : -INFINITY;
                float bv = (r - j >= 1) ? ((r - j <= LB) ? b[r - j - 1] : INFINITY) : -INFINITY;
                best = fminf(best, fmaxf(av, bv));
            }
        }
        out[r - 1] = best;
    }
}

// ---------------- K1b: tau + mode from truncated per-chunk lists ----------------
//   0  -> surplus==0: accepting ALL d<=tau (ascending m) is exactly the stable top-20
//   >0 -> exact tie budget (rank ties, ascending m)            [measure-zero case]
//   -1 -> truncation flag tripped: exact serial fallback       [~0.4 queries/run at LEN=10]
template <int NCH, int SLOTS>
__global__ __launch_bounds__(256) void knn_tau(const float* __restrict__ pd,
                                               float* __restrict__ taubuf,
                                               int* __restrict__ budgetbuf) {
    const int q = blockIdx.x * 256 + threadIdx.x;   // 128 blocks
    constexpr int CH = NN / NCH;
    constexpr int LEN = SLOTS - 1;                  // effective list length (self dropped)
    const int ch_self = (q & (NN - 1)) / CH;

    float L[NCH][LEN];
#pragma unroll
    for (int c = 0; c < NCH; ++c) {
        float raw[SLOTS];
#pragma unroll
        for (int j = 0; j < SLOTS; ++j) raw[j] = pd[(size_t)(c * SLOTS + j) * NQ + q];
        bool shift = (c == ch_self);   // drop self's exact-0 at slot 0
#pragma unroll
        for (int j = 0; j < LEN; ++j) L[c][j] = shift ? raw[j + 1] : raw[j];
    }

    float T[KK];
    mergeR<LEN, LEN, KK>(L[0], L[1], T);
#pragma unroll
    for (int c = 2; c < NCH; ++c) {
        float M[KK];
        mergeR<KK, LEN, KK>(T, L[c], M);
#pragma unroll
        for (int j = 0; j < KK; ++j) T[j] = M[j];
    }

    float tau = T[KK - 1];
    int cnt_lt = 0, cnt_eq = 0;
    bool flag = false;
#pragma unroll
    for (int c = 0; c < NCH; ++c) {
#pragma unroll
        for (int j = 0; j < LEN; ++j) {
            cnt_lt += (L[c][j] < tau) ? 1 : 0;
            cnt_eq += (L[c][j] == tau) ? 1 : 0;
        }
        flag = flag || (L[c][LEN - 1] <= tau);
    }
    int surplus = cnt_lt + cnt_eq - KK;             // >=0 when flag==0
    taubuf[q] = tau;
    budgetbuf[q] = flag ? -1 : (surplus == 0 ? 0 : (KK - cnt_lt));
}

// ---------------- K1c: collect (R15-proven lean version) ----------------
__device__ __forceinline__ int prefix_count(unsigned long long mask) {
    int r = __builtin_amdgcn_mbcnt_lo((unsigned)mask, 0);
    return __builtin_amdgcn_mbcnt_hi((unsigned)(mask >> 32), r);
}

// single-query exact collect: handles budget==0 / >0 / -1. Always fully writes erow.
__device__ void collect_one(const float4* __restrict__ pb, int n, float qx, float qy,
                            float qz, float sqn, float tau, int budget, int lane,
                            int* __restrict__ erow) {
    if (budget == 0) {
        int cnt = 0;
        for (int it = 0; it < 64; ++it) {
            int m = it * 64 + lane;
            float d = np_dist(qx, qy, qz, sqn, pb[m]);
            bool acc = (d <= tau) && (m != n);
            unsigned long long macc = __ballot(acc);
            if (macc) {
                int pos = cnt + prefix_count(macc);
                if (acc && pos < KK) erow[pos] = m;
                cnt += __popcll(macc);
            }
        }
        if (lane == 0) {   // backfill guard: edges must never retain poison
            for (int j = cnt; j < KK; ++j) erow[j] = (n + 1 + j) & (NN - 1);
        }
    } else if (budget > 0) {
        int cnt = 0, ties = 0;
        for (int it = 0; it < 64; ++it) {
            int m = it * 64 + lane;
            float d = np_dist(qx, qy, qz, sqn, pb[m]);
            bool valid = (m != n);
            bool is_lt = valid && (d < tau);
            bool is_tie = valid && (d == tau);
            unsigned long long mtie = __ballot(is_tie);
            int tie_rank = ties + prefix_count(mtie);
            bool acc = is_lt || (is_tie && tie_rank < budget);
            unsigned long long macc = __ballot(acc);
            int pos = cnt + prefix_count(macc);
            if (acc && pos < KK) erow[pos] = m;
            cnt += __popcll(macc);
            ties += __popcll(mtie);
        }
        if (lane == 0) {
            for (int j = cnt; j < KK; ++j) erow[j] = (n + 1 + j) & (NN - 1);
        }
    } else if (lane == 0) {
        // exact serial fallback: stable top-20 by (d, m) u64 keys — truncation tripped
        unsigned long long bk[KK];
#pragma unroll
        for (int j = 0; j < KK; ++j) bk[j] = ~0ULL;
        for (int m = 0; m < NN; ++m) {
            if (m == n) continue;
            float d = np_dist(qx, qy, qz, sqn, pb[m]);
            unsigned u = __float_as_uint(d);
            u ^= (unsigned)((int)u >> 31) | 0x80000000u;        // order-preserving map
            unsigned long long key = ((unsigned long long)u << 32) | (unsigned)m;
            if (key < bk[KK - 1]) {
#pragma unroll
                for (int s = KK - 1; s >= 1; --s) {
                    bool sh = bk[s - 1] > key;
                    bool here = bk[s] > key;
                    bk[s] = sh ? bk[s - 1] : (here ? key : bk[s]);
                }
                if (bk[0] > key) bk[0] = key;
            }
        }
        for (int j = 0; j < KK; ++j) erow[j] = (int)(bk[j] & (NN - 1));
    }
}

// 8 queries per wave: one candidate load feeds 8 distance tests (L2 traffic /8).
__global__ __launch_bounds__(256) void knn_collect(const float4* __restrict__ pts4,
                                                   const float* __restrict__ taubuf,
                                                   const int* __restrict__ budgetbuf,
                                                   int* __restrict__ edges) {
    const int wave = threadIdx.x >> 6;
    const int lane = threadIdx.x & 63;
    const int q0 = (blockIdx.x * 4 + wave) * 8;
    const int b = q0 >> 12;                          // 8 | 4096 -> same batch for all 8
    const float4* pb = pts4 + (size_t)b * NN;

    int nj[8], bj[8];
    float qxj[8], qyj[8], qzj[8], sqj[8], tj[8];
    int orb = 0;
#pragma unroll
    for (int j = 0; j < 8; ++j) {
        int q = q0 + j;
        nj[j] = q & (NN - 1);
        float4 me = pb[nj[j]];                       // uniform -> broadcast
        qxj[j] = me.x; qyj[j] = me.y; qzj[j] = me.z; sqj[j] = me.w;
        tj[j] = taubuf[q];
        bj[j] = budgetbuf[q];
        orb |= bj[j];
    }

    if (orb == 0) {                                  // wave-uniform fast gate
        int cnt[8] = {0, 0, 0, 0, 0, 0, 0, 0};
        for (int it = 0; it < 64; ++it) {
            int m = it * 64 + lane;
            float4 p = pb[m];                        // one coalesced b128 for 8 queries
#pragma unroll
            for (int j = 0; j < 8; ++j) {
                float d = np_dist(qxj[j], qyj[j], qzj[j], sqj[j], p);
                bool acc = (d <= tj[j]) && (m != nj[j]);
                unsigned long long mk = __ballot(acc);
                if (mk) {
                    int pos = cnt[j] + prefix_count(mk);
                    if (acc && pos < KK) edges[(size_t)(q0 + j) * KK + pos] = m;
                    cnt[j] += __popcll(mk);
                }
            }
        }
        if (lane == 0) {   // backfill guard: edges must never retain poison
#pragma unroll
            for (int j = 0; j < 8; ++j) {
                for (int t = cnt[j]; t < KK; ++t)
                    edges[(size_t)(q0 + j) * KK + t] = (nj[j] + 1 + t) & (NN - 1);
            }
        }
    } else {
        // rare: at least one query needs tie/fallback handling — do all 8 exactly
#pragma unroll
        for (int j = 0; j < 8; ++j) {
            collect_one(pb, nj[j], qxj[j], qyj[j], qzj[j], sqj[j], tj[j], bj[j], lane,
                        edges + (size_t)(q0 + j) * KK);
        }
    }
}

// ---------------- K2: projections P1 = (W1-W2)·x_n, P2 = W2·x_n ----------------
__global__ __launch_bounds__(256) void proj_kernel(const float* __restrict__ x,
                                                   const float* __restrict__ W,
                                                   float* __restrict__ P1,
                                                   float* __restrict__ P2) {
    const int wid = blockIdx.x * 4 + (threadIdx.x >> 6);  // 8192 = 512 row-blocks x 16 o-groups
    const int lane = threadIdx.x & 63;
    const int row_block = wid >> 4;
    const int og = __builtin_amdgcn_readfirstlane(wid & 15);
    const int row = row_block * 64 + lane;
    const int b = row >> 12;
    const int n = row & (NN - 1);
    const float* xb = x + (size_t)b * CC * NN;

    float p1[4] = {0.f, 0.f, 0.f, 0.f};
    float p2[4] = {0.f, 0.f, 0.f, 0.f};
#pragma unroll 8
    for (int c = 0; c < CC; ++c) {
        float xv = xb[(size_t)c * NN + n];                 // coalesced 256B
#pragma unroll
        for (int j = 0; j < 4; ++j) {
            int o = og * 4 + j;
            float w1 = W[o * 2 * CC + c];                  // scalar (s_load) — uniform
            float w2 = W[o * 2 * CC + CC + c];
            p1[j] += (w1 - w2) * xv;
            p2[j] += w2 * xv;
        }
    }
#pragma unroll
    for (int j = 0; j < 4; ++j) {
        int o = og * 4 + j;
        P1[(size_t)row * 64 + o] = p1[j];
        P2[(size_t)row * 64 + o] = p2[j];
    }
}

// ---------------- K3a: BN partial sums + per-row hmax -> transposed store into d_out --------
// XCD-batch swizzle: batch = blockIdx & 7 (L2-resident P2 per XCD); partials stay
// indexed by row-block id so downstream summation order is stable.
// ej clamped to [0,NN): a corrupt edge index can never read outside P2's batch slab.
__global__ __launch_bounds__(256) void stats_kernel(const float* __restrict__ P1,
                                                    const float* __restrict__ P2,
                                                    const int* __restrict__ edges,
                                                    float* __restrict__ partials,
                                                    float* __restrict__ out) {
    int blk = blockIdx.x;          // 512 blocks, 64 rows each
    int b = blk & 7;               // batch
    int inner = blk >> 3;          // 0..63
    int row0 = b * NN + inner * 64;
    int pblk = row0 >> 6;          // row-block id for partials (order-preserving)
    int o = threadIdx.x & 63;
    int rq = threadIdx.x >> 6;
    int n0 = row0 & (NN - 1);
    const float* P2b = P2 + (size_t)b * NN * 64;
    __shared__ float tile[64][65];
    float s = 0.f, s2 = 0.f;
    for (int rr = rq; rr < 64; rr += 4) {
        int row = row0 + rr;
        float p1 = P1[row * 64 + o];
        const int* e = edges + row * KK;
        float hm = -INFINITY;
#pragma unroll
        for (int j = 0; j < KK; ++j) {
            int ej = e[j] & (NN - 1);           // wave-uniform; clamped (safety)
            float v = p1 + P2b[ej * 64 + o];    // coalesced 256B gather (L2-resident)
            s += v;
            s2 += v * v;
            hm = fmaxf(hm, v);
        }
        tile[rr][o] = hm;
    }
    __shared__ float sh1[256], sh2[256];
    sh1[threadIdx.x] = s;
    sh2[threadIdx.x] = s2;
    __syncthreads();
    if (threadIdx.x < 64) {
        float a = sh1[threadIdx.x] + sh1[threadIdx.x + 64] + sh1[threadIdx.x + 128] + sh1[threadIdx.x + 192];
        float a2 = sh2[threadIdx.x] + sh2[threadIdx.x + 64] + sh2[threadIdx.x + 128] + sh2[threadIdx.x + 192];
        partials[pblk * 128 + threadIdx.x] = a;
        partials[pblk * 128 + 64 + threadIdx.x] = a2;
    }
    int w2 = threadIdx.x >> 6;
    int lane = threadIdx.x & 63;
    for (int o2 = w2 * 16; o2 < w2 * 16 + 16; ++o2) {
        out[((size_t)(b * 64 + o2)) * NN + n0 + lane] = tile[lane][o2];  // coalesced 256B
    }
}

// ---------------- K4: finalize BN (per-block) + elementwise act over hmax ----------------
// Each block computes A,Cv for its channel o by reducing the 512 partials rows
// (tree order; BN-const rounding shift ~1 ulp, harmless vs 0.11 threshold), then
// applies act in place. Monotone: max act == act(max h) for A>=0; exact fallback else.
__global__ __launch_bounds__(256) void out2_kernel(const float* __restrict__ P1,
                                                   const float* __restrict__ P2,
                                                   const int* __restrict__ edges,
                                                   const float* __restrict__ partials,
                                                   const float* __restrict__ gamma,
                                                   const float* __restrict__ beta,
                                                   float* __restrict__ out) {
    const int blk = blockIdx.x;        // 512 = b*64 + o
    const int b = blk >> 6;
    const int o = blk & 63;
    const int t = threadIdx.x;

    __shared__ float r1[256], r2[256];
    r1[t] = partials[t * 128 + o] + partials[(t + 256) * 128 + o];
    r2[t] = partials[t * 128 + 64 + o] + partials[(t + 256) * 128 + 64 + o];
    __syncthreads();
    for (int step = 128; step >= 1; step >>= 1) {
        if (t < step) { r1[t] += r1[t + step]; r2[t] += r2[t + step]; }
        __syncthreads();
    }
    __shared__ float sA, sC;
    if (t == 0) {
        const float M = (float)((size_t)BB * NN * KK);  // 655360
        float mean = r1[0] / M;
        float var = r2[0] / M - mean * mean;
        float inv = 1.0f / sqrtf(var + 1e-5f);
        float A = gamma[o] * inv;
        sA = A;
        sC = beta[o] - mean * A;
    }
    __syncthreads();
    const float A = sA;
    const float Cv = sC;

    float* orow = out + (size_t)blk * NN;   // out[b][o][:]
    if (A >= 0.f) {
#pragma unroll
        for (int it = 0; it < 4; ++it) {
            int idx = (it * 256 + t) * 4;
            float4 v = *(const float4*)(orow + idx);
            float h0 = v.x * A + Cv, h1 = v.y * A + Cv, h2 = v.z * A + Cv, h3 = v.w * A + Cv;
            v.x = h0 >= 0.f ? h0 : 0.2f * h0;
            v.y = h1 >= 0.f ? h1 : 0.2f * h1;
            v.z = h2 >= 0.f ? h2 : 0.2f * h2;
            v.w = h3 >= 0.f ? h3 : 0.2f * h3;
            *(float4*)(orow + idx) = v;
        }
    } else {
        // exact fallback (A<0 flips monotonicity) — never taken for this data
        const float* P2b = P2 + (size_t)b * NN * 64;
        for (int n = t; n < NN; n += 256) {
            size_t row = (size_t)b * NN + n;
            float p1 = P1[row * 64 + o];
            const int* e = edges + row * KK;
            float mx = -INFINITY;
            for (int j = 0; j < KK; ++j) {
                int ej = e[j] & (NN - 1);       // clamped (safety)
                float h = p1 + P2b[ej * 64 + o];
                float hn = h * A + Cv;
                mx = fmaxf(mx, hn >= 0.f ? hn : 0.2f * hn);
            }
            orow[n] = mx;
        }
    }
}

extern "C" void kernel_launch(void* const* d_in, const int* in_sizes, int n_in,
                              void* d_out, int out_size, void* d_ws, size_t ws_size,
                              hipStream_t stream) {
    const float* x = (const float*)d_in[0];
    const float* W = (const float*)d_in[1];
    const float* gamma = (const float*)d_in[2];
    const float* beta = (const float*)d_in[3];
    float* out = (float*)d_out;

    // De-aliased layout: only pd shares memory (with P1/P2 region, dead before proj writes).
    char* w = (char*)d_ws;
    float4* pts4      = (float4*)(w + 0);                 //   524288 B
    float*  taubuf    = (float*)(w + 524288);             //   131072 B
    int*    budgetbuf = (int*)(w + 655360);               //   131072 B
    float*  partials  = (float*)(w + 786432);             //   262144 B
    int*    edges     = (int*)(w + 1049600);              //  2621440 B
    char*   region    = w + 3671040;
    float*  P1 = (float*)region;                          //  8388608 B
    float*  P2 = P1 + (size_t)NQ * 64;                    //  8388608 B
    float*  pd = (float*)region;                          // aliases P1/P2 head

    const size_t need16 = 3671040 + (size_t)16 * 11 * NQ * 4;   // 26,739,712 B

    if (ws_size >= need16) {
        knn_part<16, 11><<<128 * 16, 256, 0, stream>>>(x, pts4, pd);
        knn_tau<16, 11><<<128, 256, 0, stream>>>(pd, taubuf, budgetbuf);
    } else {
        knn_part<8, 13><<<128 * 8, 256, 0, stream>>>(x, pts4, pd);
        knn_tau<8, 13><<<128, 256, 0, stream>>>(pd, taubuf, budgetbuf);
    }
    knn_collect<<<1024, 256, 0, stream>>>(pts4, taubuf, budgetbuf, edges);

    proj_kernel<<<2048, 256, 0, stream>>>(x, W, P1, P2);
    stats_kernel<<<512, 256, 0, stream>>>(P1, P2, edges, partials, out);
    out2_kernel<<<512, 256, 0, stream>>>(P1, P2, edges, partials, gamma, beta, out);
}